// Round 2
// baseline (4597.390 us; speedup 1.0000x reference)
//
#include <hip/hip_runtime.h>
#include <hip/hip_bf16.h>
#include <cstdint>
#include <cstddef>

typedef unsigned long long u64;
typedef unsigned int u32;

#define TILE 128
#define BK 16
#define LDSS 132   // LDS row stride in floats; write/read aliasing stays <=2-way (free per m136)
#define RR 16      // rows per block in fp64 refine

// ---------------- utility: 64-bit shfl_xor ----------------
__device__ __forceinline__ u64 shfl_xor_u64(u64 v, int m) {
    u32 lo = (u32)v;
    u32 hi = (u32)(v >> 32);
    lo = __shfl_xor(lo, m, 64);
    hi = __shfl_xor(hi, m, 64);
    return ((u64)hi << 32) | lo;
}

// merge sorted pair (m1<=m2) with sorted pair (o1<=o2) -> top-2 smallest
__device__ __forceinline__ void merge_pair(u64& m1, u64& m2, u64 o1, u64 o2) {
    u64 lo = m1 < o1 ? m1 : o1;
    u64 hi = m1 < o1 ? o1 : m1;
    u64 x  = m2 < o2 ? m2 : o2;
    m1 = lo;
    m2 = hi < x ? hi : x;
}

// ---------------- kernel 1: normalize codebooks (fp32 store, for bulk pass) ----------------
__global__ void k_codes(const float* __restrict__ cb, float* __restrict__ codes) {
    const int row = blockIdx.x;
    const int t = threadIdx.x;  // 0..127
    const float* src = cb + (size_t)row * 512 + t * 4;
    float4 v = *(const float4*)src;
    double s = (double)v.x * v.x + (double)v.y * v.y + (double)v.z * v.z + (double)v.w * v.w;
    #pragma unroll
    for (int m = 1; m < 64; m <<= 1) s += __shfl_xor(s, m, 64);
    __shared__ double sw[2];
    if ((t & 63) == 0) sw[t >> 6] = s;
    __syncthreads();
    double tot = sw[0] + sw[1];
    double inv = 1.0 / fmax(sqrt(tot), 1e-12);
    float4 o;
    o.x = (float)((double)v.x * inv);
    o.y = (float)((double)v.y * inv);
    o.z = (float)((double)v.z * inv);
    o.w = (float)((double)v.w * inv);
    *(float4*)(codes + (size_t)row * 512 + t * 4) = o;
}

// ---------------- kernel 2: projection GEMM y = x @ P (fp32, bulk) ----------------
__global__ __launch_bounds__(256) void k_proj(const float* __restrict__ A,
                                              const float* __restrict__ P,
                                              float* __restrict__ Y) {
    __shared__ float As[BK][LDSS];
    __shared__ float Bs[BK][LDSS];
    const int tid = threadIdx.x;
    const int tx = tid & 15, ty = tid >> 4;
    const int rowBase = blockIdx.x * TILE;
    const int colBase = blockIdx.y * TILE;
    const int lrow = tid >> 2;        // 0..63
    const int kq = (tid & 3) * 4;     // 0,4,8,12
    const int bn4 = (tid & 31) * 4;   // 0..124
    const int bkr = tid >> 5;         // 0..7

    float acc[8][8];
    #pragma unroll
    for (int i = 0; i < 8; i++)
        #pragma unroll
        for (int j = 0; j < 8; j++) acc[i][j] = 0.f;

    const float* a0p = A + (size_t)(rowBase + lrow) * 512;
    const float* a1p = A + (size_t)(rowBase + lrow + 64) * 512;

    for (int kt = 0; kt < 512; kt += BK) {
        __syncthreads();
        float4 va0 = *(const float4*)(a0p + kt + kq);
        float4 va1 = *(const float4*)(a1p + kt + kq);
        {
            float av0[4] = {va0.x, va0.y, va0.z, va0.w};
            float av1[4] = {va1.x, va1.y, va1.z, va1.w};
            #pragma unroll
            for (int j = 0; j < 4; j++) {
                As[kq + j][lrow] = av0[j];
                As[kq + j][lrow + 64] = av1[j];
            }
        }
        float4 vb0 = *(const float4*)(P + (size_t)(kt + bkr) * 512 + colBase + bn4);
        float4 vb1 = *(const float4*)(P + (size_t)(kt + bkr + 8) * 512 + colBase + bn4);
        *(float4*)&Bs[bkr][bn4] = vb0;
        *(float4*)&Bs[bkr + 8][bn4] = vb1;
        __syncthreads();
        #pragma unroll
        for (int k = 0; k < BK; k++) {
            float4 a0 = *(const float4*)&As[k][ty * 4];
            float4 a1 = *(const float4*)&As[k][64 + ty * 4];
            float4 b0 = *(const float4*)&Bs[k][tx * 4];
            float4 b1 = *(const float4*)&Bs[k][64 + tx * 4];
            float a[8] = {a0.x, a0.y, a0.z, a0.w, a1.x, a1.y, a1.z, a1.w};
            float b[8] = {b0.x, b0.y, b0.z, b0.w, b1.x, b1.y, b1.z, b1.w};
            #pragma unroll
            for (int i = 0; i < 8; i++)
                #pragma unroll
                for (int j = 0; j < 8; j++) acc[i][j] = fmaf(a[i], b[j], acc[i][j]);
        }
    }
    #pragma unroll
    for (int ri = 0; ri < 2; ri++)
        #pragma unroll
        for (int i = 0; i < 4; i++) {
            const int r = rowBase + ri * 64 + ty * 4 + i;
            #pragma unroll
            for (int ci = 0; ci < 2; ci++) {
                float4 o;
                o.x = acc[ri * 4 + i][ci * 4 + 0];
                o.y = acc[ri * 4 + i][ci * 4 + 1];
                o.z = acc[ri * 4 + i][ci * 4 + 2];
                o.w = acc[ri * 4 + i][ci * 4 + 3];
                *(float4*)(Y + (size_t)r * 512 + colBase + ci * 64 + tx * 4) = o;
            }
        }
}

// ---------------- kernel 3: fp32 row inverse norms of y (bulk pass scaling) ----------------
__global__ void k_norm(const float* __restrict__ Y, float* __restrict__ invn) {
    const int row = blockIdx.x * 4 + (threadIdx.x >> 6);
    const int lane = threadIdx.x & 63;
    const float* src = Y + (size_t)row * 512 + lane * 8;
    float4 v0 = *(const float4*)src;
    float4 v1 = *(const float4*)(src + 4);
    double s = (double)v0.x * v0.x + (double)v0.y * v0.y + (double)v0.z * v0.z + (double)v0.w * v0.w
             + (double)v1.x * v1.x + (double)v1.y * v1.y + (double)v1.z * v1.z + (double)v1.w * v1.w;
    #pragma unroll
    for (int m = 1; m < 64; m <<= 1) s += __shfl_xor(s, m, 64);
    if (lane == 0) invn[row] = (float)(1.0 / fmax(sqrt(s), 1e-12));
}

// ---------------- kernel 4: big fp32 GEMM + per-split top-2 candidates ----------------
// grid (256, 4): blockIdx.x = M-tile (128 rows), blockIdx.y = N-split (2048 cols).
__global__ __launch_bounds__(256) void k_top2(const float* __restrict__ Y,
                                              const float* __restrict__ invn,
                                              const float* __restrict__ codes,
                                              u64* __restrict__ part) {
    __shared__ float As[BK][LDSS];
    __shared__ float Bs[BK][LDSS];
    __shared__ u64 runs[16][8][2];   // [ty][row-in-thread][2], single-writer slots
    const int tid = threadIdx.x;
    const int tx = tid & 15, ty = tid >> 4;
    const int rowBase = blockIdx.x * TILE;
    const int split = blockIdx.y;    // 0..3
    const int lrow = tid >> 2;
    const int kq = (tid & 3) * 4;

    const float inv0 = invn[rowBase + lrow];
    const float inv1 = invn[rowBase + lrow + 64];
    const float* y0 = Y + (size_t)(rowBase + lrow) * 512;
    const float* y1 = Y + (size_t)(rowBase + lrow + 64) * 512;

    if (tx == 0) {
        #pragma unroll
        for (int r = 0; r < 8; r++) { runs[ty][r][0] = ~0ull; runs[ty][r][1] = ~0ull; }
    }

    for (int nt = 0; nt < 16; ++nt) {
        const int colBase = split * 2048 + nt * 128;
        const float* c0 = codes + (size_t)(colBase + lrow) * 512;
        const float* c1 = codes + (size_t)(colBase + lrow + 64) * 512;
        float acc[8][8];
        #pragma unroll
        for (int i = 0; i < 8; i++)
            #pragma unroll
            for (int j = 0; j < 8; j++) acc[i][j] = 0.f;

        for (int kt = 0; kt < 512; kt += BK) {
            __syncthreads();
            float4 va0 = *(const float4*)(y0 + kt + kq);
            float4 va1 = *(const float4*)(y1 + kt + kq);
            float4 vb0 = *(const float4*)(c0 + kt + kq);
            float4 vb1 = *(const float4*)(c1 + kt + kq);
            {
                float av0[4] = {va0.x * inv0, va0.y * inv0, va0.z * inv0, va0.w * inv0};
                float av1[4] = {va1.x * inv1, va1.y * inv1, va1.z * inv1, va1.w * inv1};
                float bv0[4] = {vb0.x, vb0.y, vb0.z, vb0.w};
                float bv1[4] = {vb1.x, vb1.y, vb1.z, vb1.w};
                #pragma unroll
                for (int j = 0; j < 4; j++) {
                    As[kq + j][lrow] = av0[j];
                    As[kq + j][lrow + 64] = av1[j];
                    Bs[kq + j][lrow] = bv0[j];
                    Bs[kq + j][lrow + 64] = bv1[j];
                }
            }
            __syncthreads();
            #pragma unroll
            for (int k = 0; k < BK; k++) {
                float4 a0 = *(const float4*)&As[k][ty * 4];
                float4 a1 = *(const float4*)&As[k][64 + ty * 4];
                float4 b0 = *(const float4*)&Bs[k][tx * 4];
                float4 b1 = *(const float4*)&Bs[k][64 + tx * 4];
                float a[8] = {a0.x, a0.y, a0.z, a0.w, a1.x, a1.y, a1.z, a1.w};
                float b[8] = {b0.x, b0.y, b0.z, b0.w, b1.x, b1.y, b1.z, b1.w};
                #pragma unroll
                for (int i = 0; i < 8; i++)
                    #pragma unroll
                    for (int j = 0; j < 8; j++) acc[i][j] = fmaf(a[i], b[j], acc[i][j]);
            }
        }

        // per-row top-2 of this 128-col tile, merged into running top-2
        #pragma unroll
        for (int ri = 0; ri < 2; ri++)
            #pragma unroll
            for (int i = 0; i < 4; i++) {
                const int r8 = ri * 4 + i;
                u64 m1 = ~0ull, m2 = ~0ull;
                #pragma unroll
                for (int ci = 0; ci < 2; ci++)
                    #pragma unroll
                    for (int j = 0; j < 4; j++) {
                        float f = -acc[r8][ci * 4 + j];   // minimize -dot
                        u32 fb = __float_as_uint(f);
                        fb = (fb & 0x80000000u) ? ~fb : (fb | 0x80000000u);
                        u64 key = ((u64)fb << 32) | (u32)(colBase + ci * 64 + tx * 4 + j);
                        u64 hi = m1 > key ? m1 : key;
                        m1 = m1 < key ? m1 : key;
                        m2 = m2 < hi ? m2 : hi;
                    }
                #pragma unroll
                for (int mk = 1; mk < 16; mk <<= 1) {
                    u64 o1 = shfl_xor_u64(m1, mk);
                    u64 o2 = shfl_xor_u64(m2, mk);
                    merge_pair(m1, m2, o1, o2);
                }
                if (tx == 0) {
                    u64 r1 = runs[ty][r8][0], r2 = runs[ty][r8][1];
                    merge_pair(r1, r2, m1, m2);
                    runs[ty][r8][0] = r1;
                    runs[ty][r8][1] = r2;
                }
            }
    }

    if (tx == 0) {
        #pragma unroll
        for (int ri = 0; ri < 2; ri++)
            #pragma unroll
            for (int i = 0; i < 4; i++) {
                const int r8 = ri * 4 + i;
                const size_t gr = (size_t)(rowBase + ri * 64 + ty * 4 + i);
                part[(gr * 4 + split) * 2 + 0] = runs[ty][r8][0];
                part[(gr * 4 + split) * 2 + 1] = runs[ty][r8][1];
            }
    }
}

// ---------------- kernel 5: full-fp64 refinement from RAW inputs + mask ----------------
// grid 2048 x 256. Each block: 16 rows. Recomputes y_row = x_row @ P in fp64,
// normalizes in fp64, rescores the 8 candidates against fp64-normalized raw
// codebooks -> matches an fp64 numpy reference to ~1e-15.
__global__ __launch_bounds__(256) void k_refine64(const float* __restrict__ x,
                                                  const float* __restrict__ P,
                                                  const float* __restrict__ cb,
                                                  const u64* __restrict__ part,
                                                  const int* __restrict__ mask,
                                                  int* __restrict__ out) {
    __shared__ float xs[RR][512];        // 32 KB
    __shared__ u64 cands[RR][8];
    __shared__ double nrmw[4][RR];
    __shared__ double invn[RR];
    __shared__ double wredD[4][8];
    __shared__ double wredC[4][8];
    __shared__ int bestIdx[RR];
    const int tid = threadIdx.x;
    const int m0 = blockIdx.x * RR;

    // stage x rows + candidate list
    #pragma unroll
    for (int i = 0; i < 8; i++) {
        const int off = i * 1024 + tid * 4;
        *(float4*)&xs[0][off] = *(const float4*)(x + (size_t)m0 * 512 + off);
    }
    if (tid < RR * 8) cands[tid >> 3][tid & 7] = part[(size_t)m0 * 8 + tid];
    __syncthreads();

    // fp64 projection: thread owns columns d0, d0+1 for all 16 rows
    const int d0 = tid * 2;
    double acc[RR][2];
    #pragma unroll
    for (int r = 0; r < RR; r++) { acc[r][0] = 0.0; acc[r][1] = 0.0; }
    const float* pp = P + d0;
    for (int k = 0; k < 512; k += 2) {
        float2 pa = *(const float2*)(pp + (size_t)k * 512);
        float2 pb = *(const float2*)(pp + (size_t)(k + 1) * 512);
        const double pa0 = (double)pa.x, pa1 = (double)pa.y;
        const double pb0 = (double)pb.x, pb1 = (double)pb.y;
        #pragma unroll
        for (int r = 0; r < RR; r++) {
            float2 xv = *(const float2*)&xs[r][k];
            const double x0 = (double)xv.x, x1 = (double)xv.y;
            acc[r][0] = fma(x0, pa0, acc[r][0]);
            acc[r][1] = fma(x0, pa1, acc[r][1]);
            acc[r][0] = fma(x1, pb0, acc[r][0]);
            acc[r][1] = fma(x1, pb1, acc[r][1]);
        }
    }

    // fp64 row norms
    #pragma unroll
    for (int r = 0; r < RR; r++) {
        double s = fma(acc[r][0], acc[r][0], acc[r][1] * acc[r][1]);
        #pragma unroll
        for (int mk = 1; mk < 64; mk <<= 1) s += __shfl_xor(s, mk, 64);
        if ((tid & 63) == 0) nrmw[tid >> 6][r] = s;
    }
    __syncthreads();
    if (tid < RR) {
        double t = nrmw[0][tid] + nrmw[1][tid] + nrmw[2][tid] + nrmw[3][tid];
        invn[tid] = 1.0 / fmax(sqrt(t), 1e-12);
    }
    __syncthreads();

    // rescore the 8 candidates per row in fp64 (raw codebooks, fp64 normalization)
    for (int r = 0; r < RR; r++) {
        const double xinv = invn[r];
        const double xn0 = acc[r][0] * xinv;
        const double xn1 = acc[r][1] * xinv;
        int vidx[8];
        double pd[8], pc[8];
        #pragma unroll
        for (int c = 0; c < 8; c++) {
            vidx[c] = (int)(u32)(cands[r][c] & 0xffffffffu);
            float2 cv = *(const float2*)(cb + (size_t)vidx[c] * 512 + d0);
            const double c0 = (double)cv.x, c1 = (double)cv.y;
            pd[c] = fma(c0, xn0, c1 * xn1);
            pc[c] = fma(c0, c0, c1 * c1);
        }
        #pragma unroll
        for (int mk = 1; mk < 64; mk <<= 1) {
            #pragma unroll
            for (int c = 0; c < 8; c++) {
                pd[c] += __shfl_xor(pd[c], mk, 64);
                pc[c] += __shfl_xor(pc[c], mk, 64);
            }
        }
        if ((tid & 63) == 0) {
            const int w = tid >> 6;
            #pragma unroll
            for (int c = 0; c < 8; c++) { wredD[w][c] = pd[c]; wredC[w][c] = pc[c]; }
        }
        __syncthreads();
        if (tid == 0) {
            double bs = -1.0e300;
            int bi = 0x7fffffff;
            #pragma unroll
            for (int c = 0; c < 8; c++) {
                const double D = wredD[0][c] + wredD[1][c] + wredD[2][c] + wredD[3][c];
                const double C = wredC[0][c] + wredC[1][c] + wredC[2][c] + wredC[3][c];
                const double s = D / fmax(sqrt(C), 1e-12);   // maximize normalized dot
                const int v = vidx[c];
                if (s > bs || (s == bs && v < bi)) { bs = s; bi = v; }
            }
            bestIdx[r] = bi;
        }
        __syncthreads();
    }

    if (tid < RR) out[m0 + tid] = mask[m0 + tid] ? bestIdx[tid] : 0;
}

// ---------------- launcher ----------------
extern "C" void kernel_launch(void* const* d_in, const int* in_sizes, int n_in,
                              void* d_out, int out_size, void* d_ws, size_t ws_size,
                              hipStream_t stream) {
    const float* x = (const float*)d_in[0];               // [32768,512] fp32
    const int* mask = (const int*)d_in[1];                // [32768] bool -> int32 (harness integer rule)
    const float* projection = (const float*)d_in[2];      // [512,512] fp32
    const float* codebooks = (const float*)d_in[3];       // [8192,512] fp32
    int* out = (int*)d_out;                               // [32768] int32

    // workspace layout (~86.1 MB)
    char* ws = (char*)d_ws;
    float* y     = (float*)(ws);                          // 32768*512*4 = 67108864
    float* codes = (float*)(ws + 67108864);               // 8192*512*4  = 16777216
    float* invn  = (float*)(ws + 83886080);               // 32768*4     = 131072
    u64*   part  = (u64*)  (ws + 84017152);               // 32768*4*2*8 = 2097152

    k_codes<<<8192, 128, 0, stream>>>(codebooks, codes);
    k_proj<<<dim3(256, 4), 256, 0, stream>>>(x, projection, y);
    k_norm<<<8192, 256, 0, stream>>>(y, invn);
    k_top2<<<dim3(256, 4), 256, 0, stream>>>(y, invn, codes, part);
    k_refine64<<<2048, 256, 0, stream>>>(x, projection, codebooks, part, mask, out);
}

// Round 3
// 1545.681 us; speedup vs baseline: 2.9743x; 2.9743x over previous
//
#include <hip/hip_runtime.h>
#include <hip/hip_bf16.h>
#include <cstdint>
#include <cstddef>

typedef unsigned long long u64;
typedef unsigned int u32;
typedef unsigned short ushort_t;

typedef __attribute__((ext_vector_type(8))) short short8;
typedef __attribute__((ext_vector_type(4))) float f32x4;
typedef __attribute__((ext_vector_type(8))) _Float16 half8;

#define TILE 128
#define BK 16
#define LDSS 132
#define RR 16      // rows per block in fp64 refine

// ---------------- utilities ----------------
__device__ __forceinline__ u64 shfl_xor_u64(u64 v, int m) {
    u32 lo = (u32)v;
    u32 hi = (u32)(v >> 32);
    lo = __shfl_xor(lo, m, 64);
    hi = __shfl_xor(hi, m, 64);
    return ((u64)hi << 32) | lo;
}

// manual RNE float->bf16 (no NaN inputs here)
__device__ __forceinline__ ushort_t f2bf(float f) {
    u32 u = __float_as_uint(f);
    u32 r = (u + 0x7fffu + ((u >> 16) & 1u)) >> 16;
    return (ushort_t)r;
}

// sorted-insert key k into ascending top-4 (t0<=t1<=t2<=t3), smaller = better
__device__ __forceinline__ void ins4(u64& t0, u64& t1, u64& t2, u64& t3, u64 k) {
    bool c0 = k < t0, c1 = k < t1, c2 = k < t2, c3 = k < t3;
    t3 = c3 ? (c2 ? t2 : k) : t3;
    t2 = c2 ? (c1 ? t1 : k) : t2;
    t1 = c1 ? (c0 ? t0 : k) : t1;
    t0 = c0 ? k : t0;
}

// ---------------- kernel 1: normalize codebooks -> bf16 ----------------
// grid 8192 x 128. fp64 norm, bf16 store.
__global__ void k_codes(const float* __restrict__ cb, ushort_t* __restrict__ cbf) {
    const int row = blockIdx.x;
    const int t = threadIdx.x;  // 0..127
    const float* src = cb + (size_t)row * 512 + t * 4;
    float4 v = *(const float4*)src;
    double s = (double)v.x * v.x + (double)v.y * v.y + (double)v.z * v.z + (double)v.w * v.w;
    #pragma unroll
    for (int m = 1; m < 64; m <<= 1) s += __shfl_xor(s, m, 64);
    __shared__ double sw[2];
    if ((t & 63) == 0) sw[t >> 6] = s;
    __syncthreads();
    double tot = sw[0] + sw[1];
    double inv = 1.0 / fmax(sqrt(tot), 1e-12);
    ushort4 o;
    o.x = f2bf((float)((double)v.x * inv));
    o.y = f2bf((float)((double)v.y * inv));
    o.z = f2bf((float)((double)v.z * inv));
    o.w = f2bf((float)((double)v.w * inv));
    *(ushort4*)(cbf + (size_t)row * 512 + t * 4) = o;
}

// ---------------- kernel 2: projection GEMM y = x @ P (fp32 math, bf16 out) ----------------
// Note: y is NOT normalized — per-row positive scaling does not change the argmax.
__global__ __launch_bounds__(256) void k_proj(const float* __restrict__ A,
                                              const float* __restrict__ P,
                                              ushort_t* __restrict__ Ybf) {
    __shared__ float As[BK][LDSS];
    __shared__ float Bs[BK][LDSS];
    const int tid = threadIdx.x;
    const int tx = tid & 15, ty = tid >> 4;
    const int rowBase = blockIdx.x * TILE;
    const int colBase = blockIdx.y * TILE;
    const int lrow = tid >> 2;
    const int kq = (tid & 3) * 4;
    const int bn4 = (tid & 31) * 4;
    const int bkr = tid >> 5;

    float acc[8][8];
    #pragma unroll
    for (int i = 0; i < 8; i++)
        #pragma unroll
        for (int j = 0; j < 8; j++) acc[i][j] = 0.f;

    const float* a0p = A + (size_t)(rowBase + lrow) * 512;
    const float* a1p = A + (size_t)(rowBase + lrow + 64) * 512;

    for (int kt = 0; kt < 512; kt += BK) {
        __syncthreads();
        float4 va0 = *(const float4*)(a0p + kt + kq);
        float4 va1 = *(const float4*)(a1p + kt + kq);
        {
            float av0[4] = {va0.x, va0.y, va0.z, va0.w};
            float av1[4] = {va1.x, va1.y, va1.z, va1.w};
            #pragma unroll
            for (int j = 0; j < 4; j++) {
                As[kq + j][lrow] = av0[j];
                As[kq + j][lrow + 64] = av1[j];
            }
        }
        float4 vb0 = *(const float4*)(P + (size_t)(kt + bkr) * 512 + colBase + bn4);
        float4 vb1 = *(const float4*)(P + (size_t)(kt + bkr + 8) * 512 + colBase + bn4);
        *(float4*)&Bs[bkr][bn4] = vb0;
        *(float4*)&Bs[bkr + 8][bn4] = vb1;
        __syncthreads();
        #pragma unroll
        for (int k = 0; k < BK; k++) {
            float4 a0 = *(const float4*)&As[k][ty * 4];
            float4 a1 = *(const float4*)&As[k][64 + ty * 4];
            float4 b0 = *(const float4*)&Bs[k][tx * 4];
            float4 b1 = *(const float4*)&Bs[k][64 + tx * 4];
            float a[8] = {a0.x, a0.y, a0.z, a0.w, a1.x, a1.y, a1.z, a1.w};
            float b[8] = {b0.x, b0.y, b0.z, b0.w, b1.x, b1.y, b1.z, b1.w};
            #pragma unroll
            for (int i = 0; i < 8; i++)
                #pragma unroll
                for (int j = 0; j < 8; j++) acc[i][j] = fmaf(a[i], b[j], acc[i][j]);
        }
    }
    #pragma unroll
    for (int ri = 0; ri < 2; ri++)
        #pragma unroll
        for (int i = 0; i < 4; i++) {
            const int r = rowBase + ri * 64 + ty * 4 + i;
            #pragma unroll
            for (int ci = 0; ci < 2; ci++) {
                ushort4 o;
                o.x = f2bf(acc[ri * 4 + i][ci * 4 + 0]);
                o.y = f2bf(acc[ri * 4 + i][ci * 4 + 1]);
                o.z = f2bf(acc[ri * 4 + i][ci * 4 + 2]);
                o.w = f2bf(acc[ri * 4 + i][ci * 4 + 3]);
                *(ushort4*)(Ybf + (size_t)r * 512 + colBase + ci * 64 + tx * 4) = o;
            }
        }
}

// ---------------- kernel 3: bf16 MFMA GEMM -> fp16 scores chunk ----------------
// grid (rows/128, 64). 256 thr = 4 waves, wave tile 64x64 (4x4 MFMA 16x16x32).
// LDS tiles [128 rows][64 k] bf16 with XOR swizzle: 16B slot s' = s ^ (row&7).
// global_load_lds (linear dest) + pre-swizzled global SOURCE (rule #21).
__global__ __launch_bounds__(256) void k_gemm(const ushort_t* __restrict__ X,   // [32768][512] bf16
                                              const ushort_t* __restrict__ C,   // [8192][512] bf16
                                              _Float16* __restrict__ S,         // [rows][8192] fp16
                                              int rowOff) {
    __shared__ ushort_t Ab[128 * 64];   // 16 KB
    __shared__ ushort_t Bb[128 * 64];   // 16 KB
    const int tid = threadIdx.x;
    const int lane = tid & 63;
    const int wid = tid >> 6;
    const int wm = wid & 1, wn = wid >> 1;
    const int rowBase = rowOff + blockIdx.x * 128;
    const int colBase = blockIdx.y * 128;

    // staging maps: 4 issues of 16B per thread per buffer per K-step
    const ushort_t* asrc[4];
    const ushort_t* bsrc[4];
    int ldsoff[4];
    #pragma unroll
    for (int i = 0; i < 4; i++) {
        const int L = i * 256 + tid;          // linear 16B slot 0..1023
        const int r = L >> 3;                 // tile row 0..127
        const int s = (L & 7) ^ (r & 7);      // inverse-swizzled k-slot
        asrc[i] = X + (size_t)(rowBase + r) * 512 + s * 8;
        bsrc[i] = C + (size_t)(colBase + r) * 512 + s * 8;
        ldsoff[i] = (i * 256 + (tid & ~63)) * 16;   // wave-uniform byte base
    }

    f32x4 acc[4][4];
    #pragma unroll
    for (int i = 0; i < 4; i++)
        #pragma unroll
        for (int j = 0; j < 4; j++) {
            f32x4 z = {0.f, 0.f, 0.f, 0.f};
            acc[i][j] = z;
        }

    // fragment read offsets (ushort units), swizzled
    int aoff[4][2], boff[4][2];
    #pragma unroll
    for (int ti = 0; ti < 4; ti++)
        #pragma unroll
        for (int ks = 0; ks < 2; ks++) {
            const int sa = ks * 4 + (lane >> 4);
            const int ra = wm * 64 + ti * 16 + (lane & 15);
            aoff[ti][ks] = (ra * 8 + (sa ^ (ra & 7))) * 8;
            const int rb = wn * 64 + ti * 16 + (lane & 15);
            boff[ti][ks] = (rb * 8 + (sa ^ (rb & 7))) * 8;
        }

    for (int kt = 0; kt < 512; kt += 64) {
        #pragma unroll
        for (int i = 0; i < 4; i++) {
            __builtin_amdgcn_global_load_lds(
                (const __attribute__((address_space(1))) uint32_t*)(asrc[i] + kt),
                (__attribute__((address_space(3))) uint32_t*)((char*)Ab + ldsoff[i]), 16, 0, 0);
            __builtin_amdgcn_global_load_lds(
                (const __attribute__((address_space(1))) uint32_t*)(bsrc[i] + kt),
                (__attribute__((address_space(3))) uint32_t*)((char*)Bb + ldsoff[i]), 16, 0, 0);
        }
        __syncthreads();   // drains vmcnt before any lane reads LDS
        short8 af[4][2], bfr[4][2];
        #pragma unroll
        for (int ti = 0; ti < 4; ti++)
            #pragma unroll
            for (int ks = 0; ks < 2; ks++) {
                af[ti][ks]  = *(const short8*)(Ab + aoff[ti][ks]);
                bfr[ti][ks] = *(const short8*)(Bb + boff[ti][ks]);
            }
        #pragma unroll
        for (int ks = 0; ks < 2; ks++)
            #pragma unroll
            for (int ti = 0; ti < 4; ti++)
                #pragma unroll
                for (int tj = 0; tj < 4; tj++)
                    acc[ti][tj] = __builtin_amdgcn_mfma_f32_16x16x32_bf16(
                        af[ti][ks], bfr[tj][ks], acc[ti][tj], 0, 0, 0);
        __syncthreads();   // before next-iter staging overwrites the buffers
    }

    // epilogue: C/D layout col=lane&15, row=(lane>>4)*4+reg (m89/m91)
    const int mloc = blockIdx.x * 128 + wm * 64 + (lane >> 4) * 4;   // chunk-relative
    const int nloc = colBase + wn * 64 + (lane & 15);
    #pragma unroll
    for (int ti = 0; ti < 4; ti++)
        #pragma unroll
        for (int tj = 0; tj < 4; tj++) {
            #pragma unroll
            for (int reg = 0; reg < 4; reg++)
                S[(size_t)(mloc + ti * 16 + reg) * 8192 + (nloc + tj * 16)] =
                    (_Float16)acc[ti][tj][reg];
        }
}

// ---------------- kernel 4: per-row exact top-4 scan of fp16 scores ----------------
// grid rows/4 x 256 (one wave per row). u64 key = flip(-score)<<32 | idx, smaller=better.
__global__ __launch_bounds__(256) void k_scan(const _Float16* __restrict__ S,
                                              u64* __restrict__ cands, int rowOff) {
    const int r = blockIdx.x * 4 + (threadIdx.x >> 6);
    const int lane = threadIdx.x & 63;
    const _Float16* row = S + (size_t)r * 8192;
    u64 t0 = ~0ull, t1 = ~0ull, t2 = ~0ull, t3 = ~0ull;
    for (int c = 0; c < 16; c++) {
        const int base = c * 512 + lane * 8;
        half8 v = *(const half8*)(row + base);
        #pragma unroll
        for (int j = 0; j < 8; j++) {
            float f = -(float)v[j];
            u32 fb = __float_as_uint(f);
            fb = (fb & 0x80000000u) ? ~fb : (fb | 0x80000000u);
            u64 k = ((u64)fb << 32) | (u32)(base + j);
            ins4(t0, t1, t2, t3, k);
        }
    }
    #pragma unroll
    for (int mk = 1; mk < 64; mk <<= 1) {
        u64 o0 = shfl_xor_u64(t0, mk), o1 = shfl_xor_u64(t1, mk);
        u64 o2 = shfl_xor_u64(t2, mk), o3 = shfl_xor_u64(t3, mk);
        ins4(t0, t1, t2, t3, o0);
        ins4(t0, t1, t2, t3, o1);
        ins4(t0, t1, t2, t3, o2);
        ins4(t0, t1, t2, t3, o3);
    }
    if (lane == 0) {
        u64* dst = cands + (size_t)(rowOff + r) * 4;
        dst[0] = t0; dst[1] = t1; dst[2] = t2; dst[3] = t3;
    }
}

// ---------------- kernel 5: full-fp64 refinement from RAW inputs + mask ----------------
// Unchanged math from the round-2 PASS (absmax 0.0); now 4 candidates.
__global__ __launch_bounds__(256) void k_refine64(const float* __restrict__ x,
                                                  const float* __restrict__ P,
                                                  const float* __restrict__ cb,
                                                  const u64* __restrict__ part,
                                                  const int* __restrict__ mask,
                                                  int* __restrict__ out) {
    __shared__ float xs[RR][512];
    __shared__ u64 cands[RR][4];
    __shared__ double nrmw[4][RR];
    __shared__ double invn[RR];
    __shared__ double wredD[4][4];
    __shared__ double wredC[4][4];
    __shared__ int bestIdx[RR];
    const int tid = threadIdx.x;
    const int m0 = blockIdx.x * RR;

    #pragma unroll
    for (int i = 0; i < 8; i++) {
        const int off = i * 1024 + tid * 4;
        *(float4*)&xs[0][off] = *(const float4*)(x + (size_t)m0 * 512 + off);
    }
    if (tid < RR * 4) cands[tid >> 2][tid & 3] = part[(size_t)m0 * 4 + tid];
    __syncthreads();

    const int d0 = tid * 2;
    double acc[RR][2];
    #pragma unroll
    for (int r = 0; r < RR; r++) { acc[r][0] = 0.0; acc[r][1] = 0.0; }
    const float* pp = P + d0;
    for (int k = 0; k < 512; k += 2) {
        float2 pa = *(const float2*)(pp + (size_t)k * 512);
        float2 pb = *(const float2*)(pp + (size_t)(k + 1) * 512);
        const double pa0 = (double)pa.x, pa1 = (double)pa.y;
        const double pb0 = (double)pb.x, pb1 = (double)pb.y;
        #pragma unroll
        for (int r = 0; r < RR; r++) {
            float2 xv = *(const float2*)&xs[r][k];
            const double x0 = (double)xv.x, x1 = (double)xv.y;
            acc[r][0] = fma(x0, pa0, acc[r][0]);
            acc[r][1] = fma(x0, pa1, acc[r][1]);
            acc[r][0] = fma(x1, pb0, acc[r][0]);
            acc[r][1] = fma(x1, pb1, acc[r][1]);
        }
    }

    #pragma unroll
    for (int r = 0; r < RR; r++) {
        double s = fma(acc[r][0], acc[r][0], acc[r][1] * acc[r][1]);
        #pragma unroll
        for (int mk = 1; mk < 64; mk <<= 1) s += __shfl_xor(s, mk, 64);
        if ((tid & 63) == 0) nrmw[tid >> 6][r] = s;
    }
    __syncthreads();
    if (tid < RR) {
        double t = nrmw[0][tid] + nrmw[1][tid] + nrmw[2][tid] + nrmw[3][tid];
        invn[tid] = 1.0 / fmax(sqrt(t), 1e-12);
    }
    __syncthreads();

    for (int r = 0; r < RR; r++) {
        const double xinv = invn[r];
        const double xn0 = acc[r][0] * xinv;
        const double xn1 = acc[r][1] * xinv;
        int vidx[4];
        double pd[4], pc[4];
        #pragma unroll
        for (int c = 0; c < 4; c++) {
            vidx[c] = (int)(u32)(cands[r][c] & 0xffffffffu);
            float2 cv = *(const float2*)(cb + (size_t)vidx[c] * 512 + d0);
            const double c0 = (double)cv.x, c1 = (double)cv.y;
            pd[c] = fma(c0, xn0, c1 * xn1);
            pc[c] = fma(c0, c0, c1 * c1);
        }
        #pragma unroll
        for (int mk = 1; mk < 64; mk <<= 1) {
            #pragma unroll
            for (int c = 0; c < 4; c++) {
                pd[c] += __shfl_xor(pd[c], mk, 64);
                pc[c] += __shfl_xor(pc[c], mk, 64);
            }
        }
        if ((tid & 63) == 0) {
            const int w = tid >> 6;
            #pragma unroll
            for (int c = 0; c < 4; c++) { wredD[w][c] = pd[c]; wredC[w][c] = pc[c]; }
        }
        __syncthreads();
        if (tid == 0) {
            double bs = -1.0e300;
            int bi = 0x7fffffff;
            #pragma unroll
            for (int c = 0; c < 4; c++) {
                const double D = wredD[0][c] + wredD[1][c] + wredD[2][c] + wredD[3][c];
                const double Cw = wredC[0][c] + wredC[1][c] + wredC[2][c] + wredC[3][c];
                const double s = D / fmax(sqrt(Cw), 1e-12);
                const int v = vidx[c];
                if (s > bs || (s == bs && v < bi)) { bs = s; bi = v; }
            }
            bestIdx[r] = bi;
        }
        __syncthreads();
    }

    if (tid < RR) out[m0 + tid] = mask[m0 + tid] ? bestIdx[tid] : 0;
}

// ---------------- launcher ----------------
extern "C" void kernel_launch(void* const* d_in, const int* in_sizes, int n_in,
                              void* d_out, int out_size, void* d_ws, size_t ws_size,
                              hipStream_t stream) {
    const float* x = (const float*)d_in[0];               // [32768,512] fp32
    const int* mask = (const int*)d_in[1];                // [32768] bool->int32
    const float* projection = (const float*)d_in[2];      // [512,512] fp32
    const float* codebooks = (const float*)d_in[3];       // [8192,512] fp32
    int* out = (int*)d_out;                               // [32768] int32

    // workspace: cbf 8MB | ybf 32MB | cands 1MB | scores (chunked, fp16)
    char* ws = (char*)d_ws;
    ushort_t* cbf = (ushort_t*)ws;                          // 8192*512*2  = 8 MB
    ushort_t* ybf = (ushort_t*)(ws + (8u << 20));           // 32768*512*2 = 32 MB
    u64* cands    = (u64*)(ws + (40u << 20));               // 32768*4*8   = 1 MB
    _Float16* scores = (_Float16*)(ws + (41u << 20));

    // chunk rows by available scratch (deterministic for fixed ws_size)
    size_t avail = (ws_size > (41u << 20)) ? ws_size - (41u << 20) : 0;
    long maxRows = (long)(avail / (8192 * 2));
    long rc = maxRows & ~127L;
    if (rc < 128) rc = 128;
    if (rc > 32768) rc = 32768;
    const int rowsChunk = (int)rc;

    k_codes<<<8192, 128, 0, stream>>>(codebooks, cbf);
    k_proj<<<dim3(256, 4), 256, 0, stream>>>(x, projection, ybf);
    for (int off = 0; off < 32768; off += rowsChunk) {
        const int rows = (32768 - off < rowsChunk) ? (32768 - off) : rowsChunk;
        k_gemm<<<dim3(rows / 128, 64), 256, 0, stream>>>(ybf, cbf, scores, off);
        k_scan<<<rows / 4, 256, 0, stream>>>(scores, cands, off);
    }
    k_refine64<<<2048, 256, 0, stream>>>(x, projection, codebooks, cands, mask, out);
}

// Round 4
// 999.182 us; speedup vs baseline: 4.6012x; 1.5469x over previous
//
#include <hip/hip_runtime.h>
#include <hip/hip_bf16.h>
#include <cstdint>
#include <cstddef>

typedef unsigned long long u64;
typedef unsigned int u32;
typedef unsigned short ushort_t;

typedef __attribute__((ext_vector_type(8))) short short8;
typedef __attribute__((ext_vector_type(4))) float f32x4;

#define TILE 128
#define BK 16
#define LDSS 132
#define MARGIN_TAU 5e-5   // normalized-dot margin below which we run exact fp64 fix

// ---------------- utilities ----------------
__device__ __forceinline__ u64 shfl_xor_u64(u64 v, int m) {
    u32 lo = (u32)v;
    u32 hi = (u32)(v >> 32);
    lo = __shfl_xor(lo, m, 64);
    hi = __shfl_xor(hi, m, 64);
    return ((u64)hi << 32) | lo;
}

__device__ __forceinline__ ushort_t f2bf(float f) {
    u32 u = __float_as_uint(f);
    u32 r = (u + 0x7fffu + ((u >> 16) & 1u)) >> 16;
    return (ushort_t)r;
}

// merge sorted pair (m1<=m2) with sorted pair (o1<=o2) -> top-2 smallest
__device__ __forceinline__ void merge_pair(u64& m1, u64& m2, u64 o1, u64 o2) {
    u64 lo = m1 < o1 ? m1 : o1;
    u64 hi = m1 < o1 ? o1 : m1;
    u64 x  = m2 < o2 ? m2 : o2;
    m1 = lo;
    m2 = hi < x ? hi : x;
}

// sorted-insert key k into ascending top-4
__device__ __forceinline__ void ins4(u64& t0, u64& t1, u64& t2, u64& t3, u64 k) {
    bool c0 = k < t0, c1 = k < t1, c2 = k < t2, c3 = k < t3;
    t3 = c3 ? (c2 ? t2 : k) : t3;
    t2 = c2 ? (c1 ? t1 : k) : t2;
    t1 = c1 ? (c0 ? t0 : k) : t1;
    t0 = c0 ? k : t0;
}

// sortable key from score (maximize score == minimize key), idx in low 32
__device__ __forceinline__ u64 score_key(float score, int col) {
    float f = -score;
    u32 fb = __float_as_uint(f);
    fb = (fb & 0x80000000u) ? ~fb : (fb | 0x80000000u);
    return ((u64)fb << 32) | (u32)col;
}

// ---------------- kernel 0: zero the worklist counter ----------------
__global__ void k_zero(u32* __restrict__ count) {
    if (threadIdx.x == 0) *count = 0;
}

// ---------------- kernel 1: normalize codebooks -> bf16, store fp64 ||c||^2 ----------------
__global__ void k_codes(const float* __restrict__ cb, ushort_t* __restrict__ cbf,
                        double* __restrict__ cnorm2) {
    const int row = blockIdx.x;
    const int t = threadIdx.x;  // 0..127
    const float* src = cb + (size_t)row * 512 + t * 4;
    float4 v = *(const float4*)src;
    double s = (double)v.x * v.x + (double)v.y * v.y + (double)v.z * v.z + (double)v.w * v.w;
    #pragma unroll
    for (int m = 1; m < 64; m <<= 1) s += __shfl_xor(s, m, 64);
    __shared__ double sw[2];
    if ((t & 63) == 0) sw[t >> 6] = s;
    __syncthreads();
    double tot = sw[0] + sw[1];
    double inv = 1.0 / fmax(sqrt(tot), 1e-12);
    ushort4 o;
    o.x = f2bf((float)((double)v.x * inv));
    o.y = f2bf((float)((double)v.y * inv));
    o.z = f2bf((float)((double)v.z * inv));
    o.w = f2bf((float)((double)v.w * inv));
    *(ushort4*)(cbf + (size_t)row * 512 + t * 4) = o;
    if (t == 0) cnorm2[row] = tot;
}

// ---------------- kernel 2: projection GEMM y = x @ P (fp32 math + store) ----------------
__global__ __launch_bounds__(256) void k_proj(const float* __restrict__ A,
                                              const float* __restrict__ P,
                                              float* __restrict__ Y) {
    __shared__ float As[BK][LDSS];
    __shared__ float Bs[BK][LDSS];
    const int tid = threadIdx.x;
    const int tx = tid & 15, ty = tid >> 4;
    const int rowBase = blockIdx.x * TILE;
    const int colBase = blockIdx.y * TILE;
    const int lrow = tid >> 2;
    const int kq = (tid & 3) * 4;
    const int bn4 = (tid & 31) * 4;
    const int bkr = tid >> 5;

    float acc[8][8];
    #pragma unroll
    for (int i = 0; i < 8; i++)
        #pragma unroll
        for (int j = 0; j < 8; j++) acc[i][j] = 0.f;

    const float* a0p = A + (size_t)(rowBase + lrow) * 512;
    const float* a1p = A + (size_t)(rowBase + lrow + 64) * 512;

    for (int kt = 0; kt < 512; kt += BK) {
        __syncthreads();
        float4 va0 = *(const float4*)(a0p + kt + kq);
        float4 va1 = *(const float4*)(a1p + kt + kq);
        {
            float av0[4] = {va0.x, va0.y, va0.z, va0.w};
            float av1[4] = {va1.x, va1.y, va1.z, va1.w};
            #pragma unroll
            for (int j = 0; j < 4; j++) {
                As[kq + j][lrow] = av0[j];
                As[kq + j][lrow + 64] = av1[j];
            }
        }
        float4 vb0 = *(const float4*)(P + (size_t)(kt + bkr) * 512 + colBase + bn4);
        float4 vb1 = *(const float4*)(P + (size_t)(kt + bkr + 8) * 512 + colBase + bn4);
        *(float4*)&Bs[bkr][bn4] = vb0;
        *(float4*)&Bs[bkr + 8][bn4] = vb1;
        __syncthreads();
        #pragma unroll
        for (int k = 0; k < BK; k++) {
            float4 a0 = *(const float4*)&As[k][ty * 4];
            float4 a1 = *(const float4*)&As[k][64 + ty * 4];
            float4 b0 = *(const float4*)&Bs[k][tx * 4];
            float4 b1 = *(const float4*)&Bs[k][64 + tx * 4];
            float a[8] = {a0.x, a0.y, a0.z, a0.w, a1.x, a1.y, a1.z, a1.w};
            float b[8] = {b0.x, b0.y, b0.z, b0.w, b1.x, b1.y, b1.z, b1.w};
            #pragma unroll
            for (int i = 0; i < 8; i++)
                #pragma unroll
                for (int j = 0; j < 8; j++) acc[i][j] = fmaf(a[i], b[j], acc[i][j]);
        }
    }
    #pragma unroll
    for (int ri = 0; ri < 2; ri++)
        #pragma unroll
        for (int i = 0; i < 4; i++) {
            const int r = rowBase + ri * 64 + ty * 4 + i;
            #pragma unroll
            for (int ci = 0; ci < 2; ci++) {
                float4 o;
                o.x = acc[ri * 4 + i][ci * 4 + 0];
                o.y = acc[ri * 4 + i][ci * 4 + 1];
                o.z = acc[ri * 4 + i][ci * 4 + 2];
                o.w = acc[ri * 4 + i][ci * 4 + 3];
                *(float4*)(Y + (size_t)r * 512 + colBase + ci * 64 + tx * 4) = o;
            }
        }
}

// ---------------- kernel 3: bf16 MFMA GEMM, fused per-row top-2 per block ----------------
// grid (256, 16). Block: 128 rows x 512 cols (4 col-strips of 128).
// A reg-staged from fp32 Y (cvt->bf16, swizzled ds_write); B via global_load_lds
// (linear dest + pre-swizzled source). 16B slot swizzle: s' = s ^ (row&7).
__global__ __launch_bounds__(256) void k_gemm(const float* __restrict__ Y,
                                              const ushort_t* __restrict__ C,
                                              u64* __restrict__ part2) {
    __shared__ ushort_t Ab[128 * 64];       // 16 KB
    __shared__ ushort_t Bb[128 * 64];       // 16 KB
    __shared__ u64 tmp[128][2][2];          // 4 KB  [row][wn][slot]
    __shared__ u64 runs[128][2];            // 2 KB  running per-row top-2
    const int tid = threadIdx.x;
    const int lane = tid & 63;
    const int wid = tid >> 6;
    const int wm = wid & 1, wn = wid >> 1;
    const int rowBase = blockIdx.x * 128;

    if (tid < 128) { runs[tid][0] = ~0ull; runs[tid][1] = ~0ull; }

    // staging maps
    int arow[4], ask[4];
    const ushort_t* bsrc[4];
    int aldsoff[4], bldsoff[4];
    #pragma unroll
    for (int i = 0; i < 4; i++) {
        const int L = i * 256 + tid;           // 16B slot 0..1023
        const int r = L >> 3;
        const int s = L & 7;
        arow[i] = r;
        ask[i] = s;                            // A: write swizzled dest directly
        bldsoff[i] = (i * 256 + (tid & ~63)) * 16;
        aldsoff[i] = (r * 8 + (s ^ (r & 7))) * 8;   // ushort units
        bsrc[i] = nullptr;  // filled per strip
    }

    // fragment read offsets (ushort units), swizzled
    int aoff[4][2], boff[4][2];
    #pragma unroll
    for (int ti = 0; ti < 4; ti++)
        #pragma unroll
        for (int ks = 0; ks < 2; ks++) {
            const int sa = ks * 4 + (lane >> 4);
            const int ra = wm * 64 + ti * 16 + (lane & 15);
            aoff[ti][ks] = (ra * 8 + (sa ^ (ra & 7))) * 8;
            const int rb = wn * 64 + ti * 16 + (lane & 15);
            boff[ti][ks] = (rb * 8 + (sa ^ (rb & 7))) * 8;
        }

    for (int strip = 0; strip < 4; ++strip) {
        const int colBase = blockIdx.y * 512 + strip * 128;

        f32x4 acc[4][4];
        #pragma unroll
        for (int i = 0; i < 4; i++)
            #pragma unroll
            for (int j = 0; j < 4; j++) {
                f32x4 z = {0.f, 0.f, 0.f, 0.f};
                acc[i][j] = z;
            }

        for (int kt = 0; kt < 512; kt += 64) {
            __syncthreads();   // previous-iter LDS reads (or prior strip epilogue) done
            #pragma unroll
            for (int i = 0; i < 4; i++) {
                // B: async direct-to-LDS, source pre-swizzled
                const int r = arow[i];
                const ushort_t* bs = C + (size_t)(colBase + r) * 512 + kt + (ask[i] ^ (r & 7)) * 8;
                __builtin_amdgcn_global_load_lds(
                    (const __attribute__((address_space(1))) uint32_t*)bs,
                    (__attribute__((address_space(3))) uint32_t*)((char*)Bb + bldsoff[i]), 16, 0, 0);
                // A: fp32 load + cvt + swizzled ds_write
                const float* asf = Y + (size_t)(rowBase + r) * 512 + kt + ask[i] * 8;
                float4 f0 = *(const float4*)asf;
                float4 f1 = *(const float4*)(asf + 4);
                short8 packed;
                packed[0] = (short)f2bf(f0.x); packed[1] = (short)f2bf(f0.y);
                packed[2] = (short)f2bf(f0.z); packed[3] = (short)f2bf(f0.w);
                packed[4] = (short)f2bf(f1.x); packed[5] = (short)f2bf(f1.y);
                packed[6] = (short)f2bf(f1.z); packed[7] = (short)f2bf(f1.w);
                *(short8*)(Ab + aldsoff[i]) = packed;
            }
            __syncthreads();   // drains vmcnt + lgkm before fragment reads
            short8 af[4][2], bfr[4][2];
            #pragma unroll
            for (int ti = 0; ti < 4; ti++)
                #pragma unroll
                for (int ks = 0; ks < 2; ks++) {
                    af[ti][ks]  = *(const short8*)(Ab + aoff[ti][ks]);
                    bfr[ti][ks] = *(const short8*)(Bb + boff[ti][ks]);
                }
            #pragma unroll
            for (int ks = 0; ks < 2; ks++)
                #pragma unroll
                for (int ti = 0; ti < 4; ti++)
                    #pragma unroll
                    for (int tj = 0; tj < 4; tj++)
                        acc[ti][tj] = __builtin_amdgcn_mfma_f32_16x16x32_bf16(
                            af[ti][ks], bfr[tj][ks], acc[ti][tj], 0, 0, 0);
        }

        // epilogue: per-row top-2 of this wave's 64 cols, then cross-wave merge
        #pragma unroll
        for (int ti = 0; ti < 4; ti++)
            #pragma unroll
            for (int reg = 0; reg < 4; reg++) {
                u64 m1 = ~0ull, m2 = ~0ull;
                #pragma unroll
                for (int tj = 0; tj < 4; tj++) {
                    const int col = colBase + wn * 64 + tj * 16 + (lane & 15);
                    u64 k = score_key(acc[ti][tj][reg], col);
                    u64 hi = m1 > k ? m1 : k;
                    m1 = m1 < k ? m1 : k;
                    m2 = m2 < hi ? m2 : hi;
                }
                #pragma unroll
                for (int mk = 1; mk < 16; mk <<= 1) {
                    u64 o1 = shfl_xor_u64(m1, mk);
                    u64 o2 = shfl_xor_u64(m2, mk);
                    merge_pair(m1, m2, o1, o2);
                }
                if ((lane & 15) == 0) {
                    const int mrow = wm * 64 + ti * 16 + (lane >> 4) * 4 + reg;
                    tmp[mrow][wn][0] = m1;
                    tmp[mrow][wn][1] = m2;
                }
            }
        __syncthreads();
        if (tid < 128) {
            u64 r1 = runs[tid][0], r2 = runs[tid][1];
            merge_pair(r1, r2, tmp[tid][0][0], tmp[tid][0][1]);
            merge_pair(r1, r2, tmp[tid][1][0], tmp[tid][1][1]);
            runs[tid][0] = r1;
            runs[tid][1] = r2;
        }
        // trailing sync happens at top of next strip's K-loop; final write below syncs
    }

    __syncthreads();
    if (tid < 128) {
        u64* dst = part2 + ((size_t)(rowBase + tid) * 16 + blockIdx.y) * 2;
        dst[0] = runs[tid][0];
        dst[1] = runs[tid][1];
    }
}

// ---------------- kernel 4: merge candidates + fp64 rescore from fp32 y; flag near-ties ----------------
// grid 8192 x 256 (wave per row).
__global__ __launch_bounds__(256) void k_scorepick(const u64* __restrict__ part2,
                                                   const float* __restrict__ Y,
                                                   const float* __restrict__ cb,
                                                   const double* __restrict__ cnorm2,
                                                   const int* __restrict__ mask,
                                                   int* __restrict__ out,
                                                   u32* __restrict__ wl,
                                                   u32* __restrict__ count,
                                                   u32* __restrict__ cands4) {
    const int row = blockIdx.x * 4 + (threadIdx.x >> 6);
    const int lane = threadIdx.x & 63;

    // merge 16 blocks x 2 keys -> global top-4
    u64 t0 = (lane < 32) ? part2[(size_t)row * 32 + lane] : ~0ull;
    u64 t1 = ~0ull, t2 = ~0ull, t3 = ~0ull;
    #pragma unroll
    for (int mk = 1; mk < 64; mk <<= 1) {
        u64 o0 = shfl_xor_u64(t0, mk), o1 = shfl_xor_u64(t1, mk);
        u64 o2 = shfl_xor_u64(t2, mk), o3 = shfl_xor_u64(t3, mk);
        ins4(t0, t1, t2, t3, o0);
        ins4(t0, t1, t2, t3, o1);
        ins4(t0, t1, t2, t3, o2);
        ins4(t0, t1, t2, t3, o3);
    }
    const int v0 = (int)(u32)(t0 & 0xffffffffu);
    const int v1 = (int)(u32)(t1 & 0xffffffffu);
    const int v2 = (int)(u32)(t2 & 0xffffffffu);
    const int v3 = (int)(u32)(t3 & 0xffffffffu);

    // fp64 rescore from fp32-stored y
    const float* yr = Y + (size_t)row * 512 + lane * 8;
    float4 a0 = *(const float4*)yr;
    float4 a1 = *(const float4*)(yr + 4);
    double yd[8];
    yd[0] = a0.x; yd[1] = a0.y; yd[2] = a0.z; yd[3] = a0.w;
    yd[4] = a1.x; yd[5] = a1.y; yd[6] = a1.z; yd[7] = a1.w;
    double ss = 0.0;
    #pragma unroll
    for (int e = 0; e < 8; e++) ss = fma(yd[e], yd[e], ss);
    #pragma unroll
    for (int mk = 1; mk < 64; mk <<= 1) ss += __shfl_xor(ss, mk, 64);
    const double xinv = 1.0 / fmax(sqrt(ss), 1e-12);
    double xn[8];
    #pragma unroll
    for (int e = 0; e < 8; e++) xn[e] = yd[e] * xinv;

    int vv[4] = {v0, v1, v2, v3};
    double sc[4];
    #pragma unroll
    for (int c = 0; c < 4; c++) {
        const float* cr = cb + (size_t)vv[c] * 512 + lane * 8;
        float4 c0 = *(const float4*)cr;
        float4 c1 = *(const float4*)(cr + 4);
        double d = 0.0;
        d = fma(xn[0], (double)c0.x, d); d = fma(xn[1], (double)c0.y, d);
        d = fma(xn[2], (double)c0.z, d); d = fma(xn[3], (double)c0.w, d);
        d = fma(xn[4], (double)c1.x, d); d = fma(xn[5], (double)c1.y, d);
        d = fma(xn[6], (double)c1.z, d); d = fma(xn[7], (double)c1.w, d);
        #pragma unroll
        for (int mk = 1; mk < 64; mk <<= 1) d += __shfl_xor(d, mk, 64);
        sc[c] = d / fmax(sqrt(cnorm2[vv[c]]), 1e-12);
    }

    // pick winner (max s, tie -> smaller idx) and runner-up score
    double s1 = -1.0e300, s2 = -1.0e300;
    int bi = 0x7fffffff;
    #pragma unroll
    for (int c = 0; c < 4; c++) {
        if (sc[c] > s1 || (sc[c] == s1 && vv[c] < bi)) {
            s2 = s1;
            s1 = sc[c];
            bi = vv[c];
        } else if (sc[c] > s2) {
            s2 = sc[c];
        }
    }

    if (lane == 0) {
        out[row] = mask[row] ? bi : 0;
        if (s1 - s2 < MARGIN_TAU) {
            u32 pos = atomicAdd(count, 1u);
            wl[pos] = (u32)row;
            u32* cd = cands4 + (size_t)row * 4;
            cd[0] = (u32)v0; cd[1] = (u32)v1; cd[2] = (u32)v2; cd[3] = (u32)v3;
        }
    }
}

// ---------------- kernel 5: exact fp64 fix for flagged rows ----------------
// grid 64 x 256 (256 waves, grid-stride over worklist). Per row: exact fp64
// y = x@P, normalize, rescore 4 candidates -- same math as the round-3 exact pass.
__global__ __launch_bounds__(256) void k_fix(const float* __restrict__ x,
                                             const float* __restrict__ P,
                                             const float* __restrict__ cb,
                                             const double* __restrict__ cnorm2,
                                             const u32* __restrict__ wl,
                                             const u32* __restrict__ count,
                                             const u32* __restrict__ cands4,
                                             const int* __restrict__ mask,
                                             int* __restrict__ out) {
    const int lane = threadIdx.x & 63;
    const int waveId = blockIdx.x * 4 + (threadIdx.x >> 6);
    const u32 n = *count;

    for (u32 item = waveId; item < n; item += 256) {
        const int row = (int)wl[item];
        const int c0 = lane * 8;

        // preload x row (broadcast via shuffle)
        float xr[8];
        #pragma unroll
        for (int j = 0; j < 8; j++) xr[j] = x[(size_t)row * 512 + c0 + j];

        double yd[8];
        #pragma unroll
        for (int j = 0; j < 8; j++) yd[j] = 0.0;

        for (int k8 = 0; k8 < 64; ++k8) {
            #pragma unroll
            for (int j = 0; j < 8; j++) {
                const double xk = (double)__shfl(xr[j], k8, 64);
                const int k = k8 * 8 + j;
                const float* pr = P + (size_t)k * 512 + c0;
                float4 p0 = *(const float4*)pr;
                float4 p1 = *(const float4*)(pr + 4);
                yd[0] = fma(xk, (double)p0.x, yd[0]);
                yd[1] = fma(xk, (double)p0.y, yd[1]);
                yd[2] = fma(xk, (double)p0.z, yd[2]);
                yd[3] = fma(xk, (double)p0.w, yd[3]);
                yd[4] = fma(xk, (double)p1.x, yd[4]);
                yd[5] = fma(xk, (double)p1.y, yd[5]);
                yd[6] = fma(xk, (double)p1.z, yd[6]);
                yd[7] = fma(xk, (double)p1.w, yd[7]);
            }
        }

        double ss = 0.0;
        #pragma unroll
        for (int e = 0; e < 8; e++) ss = fma(yd[e], yd[e], ss);
        #pragma unroll
        for (int mk = 1; mk < 64; mk <<= 1) ss += __shfl_xor(ss, mk, 64);
        const double xinv = 1.0 / fmax(sqrt(ss), 1e-12);
        double xn[8];
        #pragma unroll
        for (int e = 0; e < 8; e++) xn[e] = yd[e] * xinv;

        double bs = -1.0e300;
        int bi = 0x7fffffff;
        #pragma unroll
        for (int c = 0; c < 4; c++) {
            const int v = (int)cands4[(size_t)row * 4 + c];
            const float* cr = cb + (size_t)v * 512 + c0;
            float4 q0 = *(const float4*)cr;
            float4 q1 = *(const float4*)(cr + 4);
            double d = 0.0;
            d = fma(xn[0], (double)q0.x, d); d = fma(xn[1], (double)q0.y, d);
            d = fma(xn[2], (double)q0.z, d); d = fma(xn[3], (double)q0.w, d);
            d = fma(xn[4], (double)q1.x, d); d = fma(xn[5], (double)q1.y, d);
            d = fma(xn[6], (double)q1.z, d); d = fma(xn[7], (double)q1.w, d);
            #pragma unroll
            for (int mk = 1; mk < 64; mk <<= 1) d += __shfl_xor(d, mk, 64);
            const double s = d / fmax(sqrt(cnorm2[v]), 1e-12);
            if (s > bs || (s == bs && v < bi)) { bs = s; bi = v; }
        }
        if (lane == 0) out[row] = mask[row] ? bi : 0;
    }
}

// ---------------- launcher ----------------
extern "C" void kernel_launch(void* const* d_in, const int* in_sizes, int n_in,
                              void* d_out, int out_size, void* d_ws, size_t ws_size,
                              hipStream_t stream) {
    const float* x = (const float*)d_in[0];               // [32768,512] fp32
    const int* mask = (const int*)d_in[1];                // [32768] bool->int32
    const float* projection = (const float*)d_in[2];      // [512,512] fp32
    const float* codebooks = (const float*)d_in[3];       // [8192,512] fp32
    int* out = (int*)d_out;                               // [32768] int32

    // workspace layout (~81 MB; 86.1 MB proven available in round 2)
    char* ws = (char*)d_ws;
    float* y32     = (float*)(ws);                          // 64 MB
    ushort_t* cbf  = (ushort_t*)(ws + (64u << 20));         // 8 MB
    u64* part2     = (u64*)(ws + (72u << 20));              // 32768*16*2*8 = 8 MB
    u32* cands4    = (u32*)(ws + (80u << 20));              // 512 KB
    u32* wl        = (u32*)(ws + (80u << 20) + (512u << 10)); // 128 KB
    u32* count     = (u32*)(ws + (80u << 20) + (640u << 10)); // 4 B
    double* cnorm2 = (double*)(ws + (80u << 20) + (768u << 10)); // 64 KB

    k_zero<<<1, 64, 0, stream>>>(count);
    k_codes<<<8192, 128, 0, stream>>>(codebooks, cbf, cnorm2);
    k_proj<<<dim3(256, 4), 256, 0, stream>>>(x, projection, y32);
    k_gemm<<<dim3(256, 16), 256, 0, stream>>>(y32, cbf, part2);
    k_scorepick<<<8192, 256, 0, stream>>>(part2, y32, codebooks, cnorm2, mask, out,
                                          wl, count, cands4);
    k_fix<<<64, 256, 0, stream>>>(x, projection, codebooks, cnorm2, wl, count,
                                  cands4, mask, out);
}